// Round 15
// baseline (179.017 us; speedup 1.0000x reference)
//
#include <hip/hip_runtime.h>

typedef float f32x4 __attribute__((ext_vector_type(4)));
typedef short s16x8 __attribute__((ext_vector_type(8)));

#define NB_    32
#define NLC    2048
#define NLT    512
#define ND     256
#define NCHUNK 512
#define NITER  (NCHUNK / 32)

__device__ __forceinline__ unsigned short f2bf(float f) {
    union { float f; unsigned int u; } v; v.f = f;
    unsigned int r = v.u + 0x7FFFu + ((v.u >> 16) & 1u);   // RNE to bf16
    return (unsigned short)(r >> 16);
}

__device__ __forceinline__ s16x8 cvt8(float4 a, float4 c, float s) {
    s16x8 f;
    f[0]=(short)f2bf(s*a.x); f[1]=(short)f2bf(s*a.y); f[2]=(short)f2bf(s*a.z); f[3]=(short)f2bf(s*a.w);
    f[4]=(short)f2bf(s*c.x); f[5]=(short)f2bf(s*c.y); f[6]=(short)f2bf(s*c.z); f[7]=(short)f2bf(s*c.w);
    return f;
}

// async global->LDS, 16B per lane (dest = wave-uniform base + lane*16)
__device__ __forceinline__ void glds16(const void* g, void* l) {
    __builtin_amdgcn_global_load_lds(
        (const __attribute__((address_space(1))) unsigned int*)g,
        (__attribute__((address_space(3))) unsigned int*)l, 16, 0, 0);
}

// ---------------------------------------------------------------------------
// PREP3 = prep + transpose fused (coalescing-correct, unlike R12's prep2).
// Block = one 64-row x 256-d tile; grid 1280 (1024 ctx + 256 tgt).
// Phase 1: wave reads FULL rows (lane = consecutive float4, 16 rows/wave),
//          writes row-major bf16 (coalesced), LDS tile[64][264], shfl norms.
// Phase 2: 4x transpose_bf-style 64x64 subtiles -> packed panels
//          (16 scalar LDS reads -> 2 coalesced s16x8 stores per subtile).
// ---------------------------------------------------------------------------
__global__ __launch_bounds__(256) void prep3(
    const float* __restrict__ ctx, const float* __restrict__ tgt,
    float* __restrict__ norms,
    unsigned short* __restrict__ ctxb, unsigned short* __restrict__ tgtb,
    unsigned short* __restrict__ ctxTp, unsigned short* __restrict__ tgtTp)
{
    __shared__ unsigned short tile[64][264];   // pad 8 shorts: bank spread, 8B align
    const int id = blockIdx.x;
    const float* in;
    unsigned short* outb;
    unsigned short* outT;
    int nrow_off;
    if (id < 1024) {
        const int b = id >> 5, lt = id & 31;
        in   = ctx + ((size_t)b * NLC + lt * 64) * ND;
        outb = ctxb + ((size_t)b * NLC + lt * 64) * ND;
        outT = ctxTp + (((size_t)b * 32 + lt) * 256) * 64;
        nrow_off = b * NLC + lt * 64;
    } else {
        const int id2 = id - 1024;
        const int b = id2 >> 3, lt = id2 & 7;
        in   = tgt + ((size_t)b * NLT + lt * 64) * ND;
        outb = tgtb + ((size_t)b * NLT + lt * 64) * ND;
        outT = tgtTp + (((size_t)b * 8 + lt) * 256) * 64;
        nrow_off = NB_ * NLC + b * NLT + lt * 64;
    }
    const int t = threadIdx.x, wave = t >> 6, lane = t & 63;

    // ---- phase 1: 16 full rows per wave, coalesced float4 per lane
    #pragma unroll
    for (int i = 0; i < 16; ++i) {
        const int row = wave * 16 + i;
        const float4 v = *(const float4*)(in + (size_t)row * ND + lane * 4);
        const ushort4 bv = make_ushort4(f2bf(v.x), f2bf(v.y), f2bf(v.z), f2bf(v.w));
        *(ushort4*)(outb + (size_t)row * ND + lane * 4) = bv;
        *(ushort4*)&tile[row][lane * 4] = bv;
        float s = v.x * v.x + v.y * v.y + v.z * v.z + v.w * v.w;
        #pragma unroll
        for (int off = 32; off >= 1; off >>= 1) s += __shfl_xor(s, off);
        if (lane == 0) norms[nrow_off + row] = s;
    }
    __syncthreads();

    // ---- phase 2: transpose 4 subtiles of 64x64 (transpose_bf pattern)
    #pragma unroll
    for (int dt = 0; dt < 4; ++dt) {
        unsigned short buf[16];
        const int col = dt * 64 + (t >> 2);
        #pragma unroll
        for (int i = 0; i < 16; ++i)
            buf[i] = tile[(t & 3) * 16 + i][col];
        unsigned short* op = outT + (size_t)col * 64 + (t & 3) * 16;
        *(s16x8*)&op[0] = *(const s16x8*)&buf[0];
        *(s16x8*)&op[8] = *(const s16x8*)&buf[8];
    }
}

// ---------------------------------------------------------------------------
// K1 v5 (R14-proven): S = ctx.tgt^T -> weights in PACKED panel layouts.
// 32KB LDS union, occ 4; instruction-coalesced Wp/WTp stores.
// ---------------------------------------------------------------------------
__global__ __launch_bounds__(256, 4) void k1_weights(
    const unsigned short* __restrict__ ctxb, const unsigned short* __restrict__ tgtb,
    const float* __restrict__ norms,
    unsigned short* __restrict__ Wg, unsigned short* __restrict__ WTg)
{
    __shared__ __align__(16) unsigned short u[16384];   // 32KB union
    unsigned short* Alds = u;            // [128][64] swz (GEMM phase)
    unsigned short* Blds = u + 8192;     // [128][64] swz (GEMM phase)
    unsigned short* WTs  = u;            // [128 t][128 c] swz (epilogue)

    const int phys = blockIdx.x;
    const int L = (phys & 7) * 256 + (phys >> 3);   // grid 2048, bijective
    const int b = L >> 6;
    const int r = L & 63;
    const int cb = r >> 2, tb = r & 3;

    const int tid = threadIdx.x, wave = tid >> 6, lane = tid & 63;
    const int lr = lane & 15, lq = lane >> 4;
    const int cw = cb * 128 + wave * 32;

    const unsigned short* Actx = ctxb + ((size_t)b * NLC + cb * 128) * ND;
    const unsigned short* Btgt = tgtb + ((size_t)b * NLT + tb * 128) * ND;

    auto STAGE = [&](int ks) {
        #pragma unroll
        for (int i = 0; i < 4; ++i) {
            const int q = wave * 4 + i;
            const int rloc = q * 8 + (lane >> 3);
            const int gcol = (lane & 7) ^ (rloc & 7);
            glds16(Actx + (size_t)rloc * ND + ks * 64 + gcol * 8, &Alds[q * 512]);
            glds16(Btgt + (size_t)rloc * ND + ks * 64 + gcol * 8, &Blds[q * 512]);
        }
    };

    f32x4 acc[2][8];
    #pragma unroll
    for (int mf = 0; mf < 2; ++mf)
        #pragma unroll
        for (int nf = 0; nf < 8; ++nf) acc[mf][nf] = (f32x4)(0.0f);

    for (int ks = 0; ks < 4; ++ks) {
        STAGE(ks);
        __syncthreads();        // vmcnt drained -> staged data visible
        #pragma unroll
        for (int kk = 0; kk < 2; ++kk) {
            s16x8 af[2];
            #pragma unroll
            for (int mf = 0; mf < 2; ++mf) {
                const int row = wave * 32 + mf * 16 + lr;
                af[mf] = *(const s16x8*)&Alds[row * 64 + (((kk * 4 + lq) ^ (row & 7)) * 8)];
            }
            #pragma unroll
            for (int nf = 0; nf < 8; ++nf) {
                const int row = nf * 16 + lr;
                const s16x8 bf = *(const s16x8*)&Blds[row * 64 + (((kk * 4 + lq) ^ (row & 7)) * 8)];
                acc[0][nf] = __builtin_amdgcn_mfma_f32_16x16x32_bf16(af[0], bf, acc[0][nf], 0, 0, 0);
                acc[1][nf] = __builtin_amdgcn_mfma_f32_16x16x32_bf16(af[1], bf, acc[1][nf], 0, 0, 0);
            }
        }
        __syncthreads();        // all reads done before next stage / WTs reuse
    }

    float c2[2][4], t2[8];
    #pragma unroll
    for (int mf = 0; mf < 2; ++mf)
        #pragma unroll
        for (int j = 0; j < 4; ++j)
            c2[mf][j] = norms[b * NLC + cw + mf * 16 + lq * 4 + j];
    #pragma unroll
    for (int nf = 0; nf < 8; ++nf)
        t2[nf] = norms[NB_ * NLC + b * NLT + tb * 128 + nf * 16 + lr];

    // ---- weights -> WTs only (swizzle pair proven R11-R14)
    #pragma unroll
    for (int mf = 0; mf < 2; ++mf) {
        #pragma unroll
        for (int nf = 0; nf < 8; ++nf) {
            unsigned short w4[4];
            #pragma unroll
            for (int j = 0; j < 4; ++j) {
                float d2 = c2[mf][j] + t2[nf] - 2.0f * acc[mf][nf][j];
                d2 = d2 > 0.0f ? d2 : 0.0f;
                w4[j] = f2bf(__builtin_amdgcn_rcpf(1.0f + __builtin_amdgcn_sqrtf(d2)));
            }
            const int t = nf * 16 + lr;
            const int c4 = (wave * 32 + mf * 16 + lq * 4) ^ ((t & 15) << 3);
            *(ushort4*)&WTs[t * 128 + c4] = make_ushort4(w4[0], w4[1], w4[2], w4[3]);
        }
    }
    __syncthreads();   // WTs complete block-wide

    // ---- Wp write, instruction-coalesced: every store = dense 4KB span
    {
        const unsigned short* WTc = WTs;
        #pragma unroll
        for (int e = 0; e < 8; ++e) {
            const int o = (e * 256 + tid) * 8;
            const int half = o >> 13;
            const int c = (o >> 6) & 127;
            const int t0 = o & 63;          // = (tid&7)*8
            unsigned short v8[8];
            #pragma unroll
            for (int i = 0; i < 8; ++i) {
                const int t = half * 64 + t0 + i;
                v8[i] = WTc[t * 128 + (c ^ ((t & 15) << 3))];
            }
            const size_t wa =
                (((size_t)b * 8 + tb * 2 + half) * NLC + cb * 128 + c) * 64 + t0;
            *(s16x8*)&Wg[wa] = *(const s16x8*)v8;
        }
    }

    // ---- WTp write, instruction-coalesced
    {
        #pragma unroll
        for (int e = 0; e < 8; ++e) {
            const int o = (e * 256 + tid) * 8;
            const int seg = o >> 13;
            const int t = (o >> 6) & 127;
            const int c0 = o & 63;          // = (tid&7)*8, 8-aligned
            const int c8 = (seg * 64 + c0) ^ ((t & 15) << 3);   // preserves 8-align
            const size_t wa =
                (((size_t)b * 32 + cb * 2 + seg) * NLT + tb * 128 + t) * 64 + c0;
            *(s16x8*)&WTg[wa] = *(const s16x8*)&WTs[t * 128 + c8];
        }
    }
}

// ---------------------------------------------------------------------------
// K2: g2c^T GEMM, tile 128 c x 256 d, BK=64, K=512 (=t). (R11-proven.)
// A = tgtTp packed panels via global_load_lds; B = Wp packed panels.
// ---------------------------------------------------------------------------
__global__ __launch_bounds__(256, 2) void k2_gemm(
    const unsigned short* __restrict__ Atp, const unsigned short* __restrict__ Wp,
    float* __restrict__ outp)
{
    __shared__ __align__(16) unsigned short Slds[2][256 * 64];   // [d][k] swz

    const int phys = blockIdx.x;
    const int L = (phys & 7) * 64 + (phys >> 3);   // grid 512, bijective
    const int b = L >> 4, cb = L & 15;
    float* outB = outp + ((size_t)b * (NLC + NLT) + cb * 128) * ND;

    const int tid = threadIdx.x, wave = tid >> 6, lane = tid & 63;
    const int lr = lane & 15, lq = lane >> 4;

    const int srow = tid >> 3;
    const int schunk = tid & 7;

    auto STAGE = [&](int buf, int ks) {
        #pragma unroll
        for (int i = 0; i < 8; ++i) {
            const int row = i * 32 + srow;
            const int gcol = schunk ^ (row & 7);
            glds16(Atp + (((size_t)b * 8 + ks) * 256 + row) * 64 + gcol * 8,
                   &Slds[buf][(i * 32 + wave * 8) * 64]);
        }
    };

    f32x4 acc[16][2];
    #pragma unroll
    for (int mf = 0; mf < 16; ++mf) { acc[mf][0] = (f32x4)(0.0f); acc[mf][1] = (f32x4)(0.0f); }

    STAGE(0, 0);
    for (int ks = 0; ks < 8; ++ks) {
        __syncthreads();
        const int buf = ks & 1;
        if (ks < 7) STAGE(buf ^ 1, ks + 1);

        s16x8 bfr[2][2];
        #pragma unroll
        for (int j = 0; j < 2; ++j)
            #pragma unroll
            for (int kk = 0; kk < 2; ++kk)
                bfr[j][kk] = *(const s16x8*)&Wp[
                    (((size_t)b * 8 + ks) * NLC + cb * 128 + wave * 32 + j * 16 + lr) * 64
                    + kk * 32 + lq * 8];

        __builtin_amdgcn_s_setprio(1);
        #pragma unroll
        for (int kk = 0; kk < 2; ++kk) {
            #pragma unroll
            for (int mf = 0; mf < 16; ++mf) {
                const int row = mf * 16 + lr;
                const s16x8 af = *(const s16x8*)&Slds[buf][row * 64 +
                                                           (((kk * 4 + lq) ^ (row & 7)) * 8)];
                acc[mf][0] = __builtin_amdgcn_mfma_f32_16x16x32_bf16(af, bfr[0][kk], acc[mf][0], 0, 0, 0);
                acc[mf][1] = __builtin_amdgcn_mfma_f32_16x16x32_bf16(af, bfr[1][kk], acc[mf][1], 0, 0, 0);
            }
        }
        __builtin_amdgcn_s_setprio(0);
    }

    #pragma unroll
    for (int j = 0; j < 2; ++j) {
        const int col = wave * 32 + j * 16 + lr;
        float* rp = outB + (size_t)col * ND;
        #pragma unroll
        for (int mf = 0; mf < 16; ++mf) {
            const f32x4 v = acc[mf][j];
            *(float4*)(rp + mf * 16 + lq * 4) = make_float4(v[0], v[1], v[2], v[3]);
        }
    }
}

// ---------------------------------------------------------------------------
// K3V5: g2t full-K, BOTH operands LDS-staged. (R11-proven.)
// Grid 256 = (b, tb of 128t, dh of 128d); block 512 thr / 8 waves (2d x 4t).
// ---------------------------------------------------------------------------
__global__ __launch_bounds__(512, 2) void k3v5(
    const unsigned short* __restrict__ ctxTp, const unsigned short* __restrict__ WTp,
    float* __restrict__ out)
{
    __shared__ __align__(16) unsigned short Alds[2][128 * 64];   // [d][k] swz
    __shared__ __align__(16) unsigned short Blds[2][128 * 64];   // [t][k] swz

    const int phys = blockIdx.x;
    const int L = (phys & 7) * 32 + (phys >> 3);   // grid 256, bijective
    const int b = L >> 3, r = L & 7;
    const int tb = r >> 1, dh = r & 1;

    const int tid = threadIdx.x, wave = tid >> 6, lane = tid & 63;
    const int lr = lane & 15, lq = lane >> 4;
    const int wd = wave >> 2, wt = wave & 3;   // 2 d-halves x 4 t-quarters

    auto STAGE = [&](int buf, int ks) {
        #pragma unroll
        for (int i = 0; i < 2; ++i) {
            const int q = wave * 2 + i;                 // 0..15
            const int rloc = q * 8 + (lane >> 3);       // 0..127
            const int gcol = (lane & 7) ^ (rloc & 7);
            glds16(ctxTp + (((size_t)b * 32 + ks) * 256 + dh * 128 + rloc) * 64 + gcol * 8,
                   &Alds[buf][q * 512]);
            glds16(WTp + (((size_t)b * 32 + ks) * NLT + tb * 128 + rloc) * 64 + gcol * 8,
                   &Blds[buf][q * 512]);
        }
    };

    f32x4 acc[4][2];   // [mf d-frag][nf t-frag]
    #pragma unroll
    for (int mf = 0; mf < 4; ++mf) { acc[mf][0] = (f32x4)(0.0f); acc[mf][1] = (f32x4)(0.0f); }

    STAGE(0, 0);
    for (int ks = 0; ks < 32; ++ks) {
        __syncthreads();
        const int buf = ks & 1;
        if (ks < 31) STAGE(buf ^ 1, ks + 1);

        __builtin_amdgcn_s_setprio(1);
        #pragma unroll
        for (int kk = 0; kk < 2; ++kk) {
            s16x8 bfr[2];
            #pragma unroll
            for (int nf = 0; nf < 2; ++nf) {
                const int row = wt * 32 + nf * 16 + lr;
                bfr[nf] = *(const s16x8*)&Blds[buf][row * 64 + (((kk * 4 + lq) ^ (row & 7)) * 8)];
            }
            #pragma unroll
            for (int mf = 0; mf < 4; ++mf) {
                const int row = wd * 64 + mf * 16 + lr;
                const s16x8 af = *(const s16x8*)&Alds[buf][row * 64 +
                                                           (((kk * 4 + lq) ^ (row & 7)) * 8)];
                acc[mf][0] = __builtin_amdgcn_mfma_f32_16x16x32_bf16(af, bfr[0], acc[mf][0], 0, 0, 0);
                acc[mf][1] = __builtin_amdgcn_mfma_f32_16x16x32_bf16(af, bfr[1], acc[mf][1], 0, 0, 0);
            }
        }
        __builtin_amdgcn_s_setprio(0);
    }

    #pragma unroll
    for (int nf = 0; nf < 2; ++nf) {
        const int t = tb * 128 + wt * 32 + nf * 16 + lr;
        float* rp = out + ((size_t)b * (NLC + NLT) + NLC + t) * ND + dh * 128 + wd * 64;
        #pragma unroll
        for (int mf = 0; mf < 4; ++mf) {
            const f32x4 v = acc[mf][nf];
            *(float4*)(rp + mf * 16 + lq * 4) = make_float4(v[0], v[1], v[2], v[3]);
        }
    }
}

// ===========================================================================
// R4 fused fallback (proven-correct) for small workspaces.
// ===========================================================================
__global__ __launch_bounds__(256) void zero_g2t(float* __restrict__ out) {
    const int g = blockIdx.x * 256 + threadIdx.x;
    #pragma unroll
    for (int k = 0; k < 4; ++k) {
        const int i = g + k * 262144;
        const int bb = i >> 15;
        const int off = i & 32767;
        *(float4*)(out + ((size_t)bb * (NLC + NLT) + NLC) * ND + (size_t)off * 4) =
            make_float4(0.f, 0.f, 0.f, 0.f);
    }
}

__global__ __launch_bounds__(256) void reduce_g2t(const float* __restrict__ part,
                                                  float* __restrict__ out) {
    const int g = blockIdx.x * 256 + threadIdx.x;
    #pragma unroll
    for (int k = 0; k < 4; ++k) {
        const int i = g + k * 262144;
        const int b = i >> 15;
        const int rem = i & 32767;
        const int row = rem >> 6;
        const int d4 = (rem & 63) * 4;
        const int mb = row >> 7, rr = row & 127;
        const size_t base = ((size_t)(b * 16 + mb * 4) * 32768) + (size_t)rr * 256 + d4;
        float4 s0 = *(const float4*)(part + base);
        float4 s1 = *(const float4*)(part + base + 32768);
        float4 s2 = *(const float4*)(part + base + 65536);
        float4 s3 = *(const float4*)(part + base + 98304);
        *(float4*)(out + ((size_t)b * (NLC + NLT) + NLC + row) * ND + d4) =
            make_float4(s0.x + s1.x + s2.x + s3.x, s0.y + s1.y + s2.y + s3.y,
                        s0.z + s1.z + s2.z + s3.z, s0.w + s1.w + s2.w + s3.w);
    }
}

__global__ __launch_bounds__(256, 2) void fused_dist_attn(
    const float* __restrict__ ctx, const float* __restrict__ tgt,
    float* __restrict__ out, float* __restrict__ part)
{
    __shared__ __align__(16) unsigned short Klds[2][32 * 256];
    __shared__ __align__(16) unsigned short VTlds[2][256 * 32];
    __shared__ __align__(16) unsigned short Wlds[4 * 32 * 32];
    __shared__ unsigned int KextLds[2][32];

    const int phys = blockIdx.x;
    const int L = (phys & 7) * 128 + (phys >> 3);
    const int isB = (L & 1) == 0;
    const int idx = L >> 1;
    const int b = idx >> 4;
    const float *Q, *KV;
    size_t outbase;
    if (isB) {
        const int mb = (idx >> 2) & 3, nc = idx & 3;
        Q = tgt + ((size_t)b * NLT + mb * 128) * ND;
        KV = ctx + ((size_t)b * NLC + nc * NCHUNK) * ND;
        outbase = ((size_t)b * (NLC + NLT) + NLC + mb * 128) * ND;
    } else {
        const int mb = idx & 15;
        Q = ctx + ((size_t)b * NLC + mb * 128) * ND;
        KV = tgt + (size_t)b * NLT * ND;
        outbase = ((size_t)b * (NLC + NLT) + mb * 128) * ND;
    }

    const int tid = threadIdx.x, wave = tid >> 6, lane = tid & 63;
    const int lr = lane & 15, lq = lane >> 4;

    s16x8 qf[2][8];
    s16x8 qe[2];
    #pragma unroll
    for (int mf = 0; mf < 2; ++mf) {
        const float* qrow = Q + (size_t)(wave * 32 + mf * 16 + lr) * ND;
        float q2 = 0.0f;
        #pragma unroll
        for (int kk = 0; kk < 8; ++kk) {
            const float4 a = *(const float4*)(qrow + kk * 32 + lq * 8);
            const float4 c = *(const float4*)(qrow + kk * 32 + lq * 8 + 4);
            q2 += a.x*a.x + a.y*a.y + a.z*a.z + a.w*a.w;
            q2 += c.x*c.x + c.y*c.y + c.z*c.z + c.w*c.w;
            qf[mf][kk] = cvt8(a, c, -2.0f);
        }
        q2 += __shfl_xor(q2, 16);
        q2 += __shfl_xor(q2, 32);
        union { unsigned int u[4]; s16x8 v; } qu;
        qu.u[0] = (lq == 0) ? (0x3F80u | ((unsigned int)f2bf(q2) << 16)) : 0u;
        qu.u[1] = 0u; qu.u[2] = 0u; qu.u[3] = 0u;
        qe[mf] = qu.v;
    }

    f32x4 acc[2][16];
    #pragma unroll
    for (int mf = 0; mf < 2; ++mf)
        #pragma unroll
        for (int dt = 0; dt < 16; ++dt)
            acc[mf][dt] = (f32x4)(0.0f);

    const int r4 = 8 * wave + 4 * (lane & 1);
    const int d8 = (lane >> 1) * 8;
    float4 ldr[4][2];

    auto LOADT = [&](int n0) {
        #pragma unroll
        for (int rr = 0; rr < 4; ++rr)
            #pragma unroll
            for (int h = 0; h < 2; ++h)
                ldr[rr][h] = *(const float4*)(KV + (size_t)(n0 + r4 + rr) * ND + d8 + 4 * h);
    };

    auto WRITET = [&](int sel) {
        float ps[4];
        unsigned short kb[4][8];
        #pragma unroll
        for (int rr = 0; rr < 4; ++rr) {
            const float4 a = ldr[rr][0], c = ldr[rr][1];
            ps[rr] = a.x*a.x + a.y*a.y + a.z*a.z + a.w*a.w
                   + c.x*c.x + c.y*c.y + c.z*c.z + c.w*c.w;
            kb[rr][0]=f2bf(a.x); kb[rr][1]=f2bf(a.y); kb[rr][2]=f2bf(a.z); kb[rr][3]=f2bf(a.w);
            kb[rr][4]=f2bf(c.x); kb[rr][5]=f2bf(c.y); kb[rr][6]=f2bf(c.z); kb[rr][7]=f2bf(c.w);
            const int rx = r4 + rr;
            *(s16x8*)&Klds[sel][rx * 256 + (d8 ^ ((rx & 7) << 3))] = *(const s16x8*)kb[rr];
        }
        #pragma unroll
        for (int dd = 0; dd < 8; ++dd) {
            const int d = d8 + dd;
            *(ushort4*)&VTlds[sel][d * 32 + (r4 ^ (((d >> 3) & 3) << 3))] =
                make_ushort4(kb[0][dd], kb[1][dd], kb[2][dd], kb[3][dd]);
        }
        #pragma unroll
        for (int rr = 0; rr < 4; ++rr) {
            ps[rr] += __shfl_xor(ps[rr], 2);
            ps[rr] += __shfl_xor(ps[rr], 4);
            ps[rr] += __shfl_xor(ps[rr], 8);
            ps[rr] += __shfl_xor(ps[rr], 16);
            ps[rr] += __shfl_xor(ps[rr], 32);
        }
        if (lane < 2) {
            #pragma unroll
            for (int rr = 0; rr < 4; ++rr)
                KextLds[sel][8 * wave + 4 * lane + rr] =
                    (unsigned int)f2bf(ps[rr]) | 0x3F800000u;
        }
    };

    LOADT(0);
    WRITET(0);

    #pragma unroll 2
    for (int t = 0; t < NITER; ++t) {
        __syncthreads();
        const int sel = t & 1;
        if (t + 1 < NITER) LOADT((t + 1) * 32);

        unsigned int p0 = 0u, p1 = 0u;
        if (lq == 0) { p0 = KextLds[sel][lr]; p1 = KextLds[sel][16 + lr]; }
        union { unsigned int u[4]; s16x8 v; } keu0, keu1;
        keu0.u[0] = p0; keu0.u[1] = 0; keu0.u[2] = 0; keu0.u[3] = 0;
        keu1.u[0] = p1; keu1.u[1] = 0; keu1.u[2] = 0; keu1.u[3] = 0;

        f32x4 sacc[2][2];
        sacc[0][0] = (f32x4)(0.0f); sacc[0][1] = (f32x4)(0.0f);
        sacc[1][0] = (f32x4)(0.0f); sacc[1][1] = (f32x4)(0.0f);
        __builtin_amdgcn_s_setprio(1);
        #pragma unroll
        for (int kk = 0; kk < 8; ++kk) {
            const int cs = (kk * 32 + lq * 8) ^ ((lr & 7) << 3);
            const s16x8 kf0 = *(const s16x8*)&Klds[sel][lr * 256 + cs];
            const s16x8 kf1 = *(const s16x8*)&Klds[sel][(16 + lr) * 256 + cs];
            sacc[0][0] = __builtin_amdgcn_mfma_f32_16x16x32_bf16(kf0, qf[0][kk], sacc[0][0], 0, 0, 0);
            sacc[0][1] = __builtin_amdgcn_mfma_f32_16x16x32_bf16(kf0, qf[1][kk], sacc[0][1], 0, 0, 0);
            sacc[1][0] = __builtin_amdgcn_mfma_f32_16x16x32_bf16(kf1, qf[0][kk], sacc[1][0], 0, 0, 0);
            sacc[1][1] = __builtin_amdgcn_mfma_f32_16x16x32_bf16(kf1, qf[1][kk], sacc[1][1], 0, 0, 0);
        }
        sacc[0][0] = __builtin_amdgcn_mfma_f32_16x16x32_bf16(keu0.v, qe[0], sacc[0][0], 0, 0, 0);
        sacc[0][1] = __builtin_amdgcn_mfma_f32_16x16x32_bf16(keu0.v, qe[1], sacc[0][1], 0, 0, 0);
        sacc[1][0] = __builtin_amdgcn_mfma_f32_16x16x32_bf16(keu1.v, qe[0], sacc[1][0], 0, 0, 0);
        sacc[1][1] = __builtin_amdgcn_mfma_f32_16x16x32_bf16(keu1.v, qe[1], sacc[1][1], 0, 0, 0);
        __builtin_amdgcn_s_setprio(0);

        #pragma unroll
        for (int ns = 0; ns < 2; ++ns) {
            #pragma unroll
            for (int mf = 0; mf < 2; ++mf) {
                unsigned short w4[4];
                #pragma unroll
                for (int j = 0; j < 4; ++j) {
                    float d2 = sacc[ns][mf][j];
                    d2 = d2 > 0.0f ? d2 : 0.0f;
                    w4[j] = f2bf(__builtin_amdgcn_rcpf(1.0f + __builtin_amdgcn_sqrtf(d2)));
                }
                const int row = mf * 16 + lr;
                const int col = (ns * 16 + lq * 4) ^ ((row & 3) << 3);
                *(ushort4*)&Wlds[wave * 1024 + row * 32 + col] =
                    make_ushort4(w4[0], w4[1], w4[2], w4[3]);
            }
        }

        s16x8 wfr[2];
        #pragma unroll
        for (int mf = 0; mf < 2; ++mf)
            wfr[mf] = *(const s16x8*)&Wlds[wave * 1024 + (mf * 16 + lr) * 32 +
                                           ((lq * 8) ^ ((lr & 3) << 3))];
        __builtin_amdgcn_s_setprio(1);
        #pragma unroll
        for (int dt = 0; dt < 16; ++dt) {
            const int vr = dt * 16 + lr;
            const s16x8 vf = *(const s16x8*)&VTlds[sel][vr * 32 +
                                                        ((lq * 8) ^ (((vr >> 3) & 3) << 3))];
            acc[0][dt] = __builtin_amdgcn_mfma_f32_16x16x32_bf16(vf, wfr[0], acc[0][dt], 0, 0, 0);
            acc[1][dt] = __builtin_amdgcn_mfma_f32_16x16x32_bf16(vf, wfr[1], acc[1][dt], 0, 0, 0);
        }
        __builtin_amdgcn_s_setprio(0);

        if (t + 1 < NITER) WRITET(sel ^ 1);
    }

    if (isB) {
        if (part) {
            float* p = part + (size_t)idx * 32768;
            #pragma unroll
            for (int mf = 0; mf < 2; ++mf) {
                const size_t rowbase = (size_t)(wave * 32 + mf * 16 + lr) * ND;
                #pragma unroll
                for (int dt = 0; dt < 16; ++dt) {
                    const f32x4 v = acc[mf][dt];
                    *(float4*)(p + rowbase + dt * 16 + lq * 4) = make_float4(v[0], v[1], v[2], v[3]);
                }
            }
        } else {
            #pragma unroll
            for (int mf = 0; mf < 2; ++mf) {
                float* rowp = out + outbase + (size_t)(wave * 32 + mf * 16 + lr) * ND;
                #pragma unroll
                for (int dt = 0; dt < 16; ++dt)
                    #pragma unroll
                    for (int j = 0; j < 4; ++j)
                        atomicAdd(rowp + dt * 16 + lq * 4 + j, acc[mf][dt][j]);
            }
        }
    } else {
        #pragma unroll
        for (int mf = 0; mf < 2; ++mf) {
            const size_t rowbase = outbase + (size_t)(wave * 32 + mf * 16 + lr) * ND;
            #pragma unroll
            for (int dt = 0; dt < 16; ++dt) {
                const f32x4 v = acc[mf][dt];
                *(float4*)(out + rowbase + dt * 16 + lq * 4) = make_float4(v[0], v[1], v[2], v[3]);
            }
        }
    }
}

extern "C" void kernel_launch(void* const* d_in, const int* in_sizes, int n_in,
                              void* d_out, int out_size, void* d_ws, size_t ws_size,
                              hipStream_t stream) {
    const float* ctx = (const float*)d_in[0];   // [32, 2048, 256] fp32
    const float* tgt = (const float*)d_in[1];   // [32, 512, 256] fp32
    float* out = (float*)d_out;                 // [32, 2560, 256] fp32

    const size_t OFF_NORMS = 0;
    const size_t OFF_CTXB  = 327680;
    const size_t OFF_TGTB  = OFF_CTXB + 33554432;
    const size_t OFF_CTXT  = OFF_TGTB + 8388608;
    const size_t OFF_TGTT  = OFF_CTXT + 33554432;
    const size_t OFF_W     = OFF_TGTT + 8388608;
    const size_t OFF_WT    = OFF_W + 67108864;
    const size_t NEED_NEW  = OFF_WT + 67108864;   // 218,431,488 (proven available)

    char* ws = (char*)d_ws;
    if (ws_size >= NEED_NEW) {
        float* norms = (float*)(ws + OFF_NORMS);
        unsigned short* ctxb  = (unsigned short*)(ws + OFF_CTXB);
        unsigned short* tgtb  = (unsigned short*)(ws + OFF_TGTB);
        unsigned short* ctxTp = (unsigned short*)(ws + OFF_CTXT);
        unsigned short* tgtTp = (unsigned short*)(ws + OFF_TGTT);
        unsigned short* Wg    = (unsigned short*)(ws + OFF_W);
        unsigned short* WTg   = (unsigned short*)(ws + OFF_WT);

        prep3<<<1280, 256, 0, stream>>>(ctx, tgt, norms, ctxb, tgtb, ctxTp, tgtTp);
        k1_weights<<<2048, 256, 0, stream>>>(ctxb, tgtb, norms, Wg, WTg);
        k2_gemm<<<512, 256, 0, stream>>>(tgtTp, Wg, out);
        k3v5<<<256, 512, 0, stream>>>(ctxTp, WTg, out);
    } else {
        const size_t need = (size_t)512 * 128 * 256 * 4;
        if (ws_size >= need) {
            float* part = (float*)d_ws;
            fused_dist_attn<<<1024, 256, 0, stream>>>(ctx, tgt, out, part);
            reduce_g2t<<<1024, 256, 0, stream>>>(part, out);
        } else {
            zero_g2t<<<1024, 256, 0, stream>>>(out);
            fused_dist_attn<<<1024, 256, 0, stream>>>(ctx, tgt, out, nullptr);
        }
    }
}

// Round 16
// 171.607 us; speedup vs baseline: 1.0432x; 1.0432x over previous
//
#include <hip/hip_runtime.h>

typedef float f32x4 __attribute__((ext_vector_type(4)));
typedef short s16x8 __attribute__((ext_vector_type(8)));

#define NB_    32
#define NLC    2048
#define NLT    512
#define ND     256
#define NCHUNK 512
#define NITER  (NCHUNK / 32)

__device__ __forceinline__ unsigned short f2bf(float f) {
    union { float f; unsigned int u; } v; v.f = f;
    unsigned int r = v.u + 0x7FFFu + ((v.u >> 16) & 1u);   // RNE to bf16
    return (unsigned short)(r >> 16);
}

__device__ __forceinline__ s16x8 cvt8(float4 a, float4 c, float s) {
    s16x8 f;
    f[0]=(short)f2bf(s*a.x); f[1]=(short)f2bf(s*a.y); f[2]=(short)f2bf(s*a.z); f[3]=(short)f2bf(s*a.w);
    f[4]=(short)f2bf(s*c.x); f[5]=(short)f2bf(s*c.y); f[6]=(short)f2bf(s*c.z); f[7]=(short)f2bf(s*c.w);
    return f;
}

// async global->LDS, 16B per lane (dest = wave-uniform base + lane*16)
__device__ __forceinline__ void glds16(const void* g, void* l) {
    __builtin_amdgcn_global_load_lds(
        (const __attribute__((address_space(1))) unsigned int*)g,
        (__attribute__((address_space(3))) unsigned int*)l, 16, 0, 0);
}

// ---------------------------------------------------------------------------
// Prep: bf16 copies of ctx/tgt + row squared-norms. One wave per row. (R11)
// ---------------------------------------------------------------------------
__global__ __launch_bounds__(256) void prep_kernel(
    const float* __restrict__ ctx, const float* __restrict__ tgt,
    float* __restrict__ norms,
    unsigned short* __restrict__ ctxb, unsigned short* __restrict__ tgtb)
{
    const int wave = threadIdx.x >> 6;
    const int lane = threadIdx.x & 63;
    const int rid = blockIdx.x * 4 + wave;
    const float* row;
    unsigned short* drow;
    if (rid < NB_ * NLC) { row = ctx + (size_t)rid * ND; drow = ctxb + (size_t)rid * ND; }
    else { row = tgt + (size_t)(rid - NB_ * NLC) * ND; drow = tgtb + (size_t)(rid - NB_ * NLC) * ND; }
    const float4 v = *(const float4*)(row + lane * 4);
    *(ushort4*)(drow + lane * 4) = make_ushort4(f2bf(v.x), f2bf(v.y), f2bf(v.z), f2bf(v.w));
    float s = v.x * v.x + v.y * v.y + v.z * v.z + v.w * v.w;
    #pragma unroll
    for (int off = 32; off >= 1; off >>= 1) s += __shfl_xor(s, off);
    if (lane == 0) norms[rid] = s;
}

// ---------------------------------------------------------------------------
// Transpose to PACKED panel layouts (R11):
//   ctxTp[b][cs=c/64][256 d][64]   tgtTp[b][ts=t/64][256 d][64]
// ---------------------------------------------------------------------------
__global__ __launch_bounds__(256) void transpose_bf(
    const unsigned short* __restrict__ ctxb, const unsigned short* __restrict__ tgtb,
    unsigned short* __restrict__ ctxTp, unsigned short* __restrict__ tgtTp)
{
    __shared__ unsigned short tile[64][72];
    const int id = blockIdx.x;
    const unsigned short* in;
    unsigned short* outp;
    const int t = threadIdx.x;
    if (id < 4096) {
        const int b = id >> 7, r = id & 127, lt = r >> 2, dt = r & 3;
        in   = ctxb + ((size_t)b * NLC + lt * 64) * ND + dt * 64;
        outp = ctxTp + (((size_t)b * 32 + lt) * 256 + dt * 64) * 64;
    } else {
        const int id2 = id - 4096;
        const int b = id2 >> 5, r = id2 & 31, lt = r >> 2, dt = r & 3;
        in   = tgtb + ((size_t)b * NLT + lt * 64) * ND + dt * 64;
        outp = tgtTp + (((size_t)b * 8 + lt) * 256 + dt * 64) * 64;
    }
    const int r0 = t >> 2, c0 = t & 3;
    const s16x8 v0 = *(const s16x8*)&in[(size_t)r0 * ND + c0 * 8];
    const s16x8 v1 = *(const s16x8*)&in[(size_t)r0 * ND + (c0 + 4) * 8];
    *(s16x8*)&tile[r0][c0 * 8] = v0;
    *(s16x8*)&tile[r0][(c0 + 4) * 8] = v1;
    __syncthreads();
    unsigned short buf[16];
    #pragma unroll
    for (int i = 0; i < 16; ++i) buf[i] = tile[(t & 3) * 16 + i][t >> 2];
    unsigned short* op = outp + (size_t)(t >> 2) * 64 + (t & 3) * 16;
    *(s16x8*)&op[0] = *(const s16x8*)&buf[0];
    *(s16x8*)&op[8] = *(const s16x8*)&buf[8];
}

// ---------------------------------------------------------------------------
// K1 v5 (R14-proven): S = ctx.tgt^T -> weights in PACKED panel layouts.
// 32KB LDS union, occ 4; instruction-coalesced Wp/WTp stores (dense 4KB spans).
// ---------------------------------------------------------------------------
__global__ __launch_bounds__(256, 4) void k1_weights(
    const unsigned short* __restrict__ ctxb, const unsigned short* __restrict__ tgtb,
    const float* __restrict__ norms,
    unsigned short* __restrict__ Wg, unsigned short* __restrict__ WTg)
{
    __shared__ __align__(16) unsigned short u[16384];   // 32KB union
    unsigned short* Alds = u;            // [128][64] swz (GEMM phase)
    unsigned short* Blds = u + 8192;     // [128][64] swz (GEMM phase)
    unsigned short* WTs  = u;            // [128 t][128 c] swz (epilogue)

    const int phys = blockIdx.x;
    const int L = (phys & 7) * 256 + (phys >> 3);   // grid 2048, bijective
    const int b = L >> 6;
    const int r = L & 63;
    const int cb = r >> 2, tb = r & 3;

    const int tid = threadIdx.x, wave = tid >> 6, lane = tid & 63;
    const int lr = lane & 15, lq = lane >> 4;
    const int cw = cb * 128 + wave * 32;

    const unsigned short* Actx = ctxb + ((size_t)b * NLC + cb * 128) * ND;
    const unsigned short* Btgt = tgtb + ((size_t)b * NLT + tb * 128) * ND;

    auto STAGE = [&](int ks) {
        #pragma unroll
        for (int i = 0; i < 4; ++i) {
            const int q = wave * 4 + i;
            const int rloc = q * 8 + (lane >> 3);
            const int gcol = (lane & 7) ^ (rloc & 7);
            glds16(Actx + (size_t)rloc * ND + ks * 64 + gcol * 8, &Alds[q * 512]);
            glds16(Btgt + (size_t)rloc * ND + ks * 64 + gcol * 8, &Blds[q * 512]);
        }
    };

    f32x4 acc[2][8];
    #pragma unroll
    for (int mf = 0; mf < 2; ++mf)
        #pragma unroll
        for (int nf = 0; nf < 8; ++nf) acc[mf][nf] = (f32x4)(0.0f);

    for (int ks = 0; ks < 4; ++ks) {
        STAGE(ks);
        __syncthreads();        // vmcnt drained -> staged data visible
        #pragma unroll
        for (int kk = 0; kk < 2; ++kk) {
            s16x8 af[2];
            #pragma unroll
            for (int mf = 0; mf < 2; ++mf) {
                const int row = wave * 32 + mf * 16 + lr;
                af[mf] = *(const s16x8*)&Alds[row * 64 + (((kk * 4 + lq) ^ (row & 7)) * 8)];
            }
            #pragma unroll
            for (int nf = 0; nf < 8; ++nf) {
                const int row = nf * 16 + lr;
                const s16x8 bf = *(const s16x8*)&Blds[row * 64 + (((kk * 4 + lq) ^ (row & 7)) * 8)];
                acc[0][nf] = __builtin_amdgcn_mfma_f32_16x16x32_bf16(af[0], bf, acc[0][nf], 0, 0, 0);
                acc[1][nf] = __builtin_amdgcn_mfma_f32_16x16x32_bf16(af[1], bf, acc[1][nf], 0, 0, 0);
            }
        }
        __syncthreads();        // all reads done before next stage / WTs reuse
    }

    float c2[2][4], t2[8];
    #pragma unroll
    for (int mf = 0; mf < 2; ++mf)
        #pragma unroll
        for (int j = 0; j < 4; ++j)
            c2[mf][j] = norms[b * NLC + cw + mf * 16 + lq * 4 + j];
    #pragma unroll
    for (int nf = 0; nf < 8; ++nf)
        t2[nf] = norms[NB_ * NLC + b * NLT + tb * 128 + nf * 16 + lr];

    // ---- weights -> WTs only (swizzle pair proven R11-R14)
    #pragma unroll
    for (int mf = 0; mf < 2; ++mf) {
        #pragma unroll
        for (int nf = 0; nf < 8; ++nf) {
            unsigned short w4[4];
            #pragma unroll
            for (int j = 0; j < 4; ++j) {
                float d2 = c2[mf][j] + t2[nf] - 2.0f * acc[mf][nf][j];
                d2 = d2 > 0.0f ? d2 : 0.0f;
                w4[j] = f2bf(__builtin_amdgcn_rcpf(1.0f + __builtin_amdgcn_sqrtf(d2)));
            }
            const int t = nf * 16 + lr;
            const int c4 = (wave * 32 + mf * 16 + lq * 4) ^ ((t & 15) << 3);
            *(ushort4*)&WTs[t * 128 + c4] = make_ushort4(w4[0], w4[1], w4[2], w4[3]);
        }
    }
    __syncthreads();   // WTs complete block-wide

    // ---- Wp write, instruction-coalesced: every store = dense 4KB span
    {
        const unsigned short* WTc = WTs;
        #pragma unroll
        for (int e = 0; e < 8; ++e) {
            const int o = (e * 256 + tid) * 8;
            const int half = o >> 13;
            const int c = (o >> 6) & 127;
            const int t0 = o & 63;          // = (tid&7)*8
            unsigned short v8[8];
            #pragma unroll
            for (int i = 0; i < 8; ++i) {
                const int t = half * 64 + t0 + i;
                v8[i] = WTc[t * 128 + (c ^ ((t & 15) << 3))];
            }
            const size_t wa =
                (((size_t)b * 8 + tb * 2 + half) * NLC + cb * 128 + c) * 64 + t0;
            *(s16x8*)&Wg[wa] = *(const s16x8*)v8;
        }
    }

    // ---- WTp write, instruction-coalesced
    {
        #pragma unroll
        for (int e = 0; e < 8; ++e) {
            const int o = (e * 256 + tid) * 8;
            const int seg = o >> 13;
            const int t = (o >> 6) & 127;
            const int c0 = o & 63;          // = (tid&7)*8, 8-aligned
            const int c8 = (seg * 64 + c0) ^ ((t & 15) << 3);   // preserves 8-align
            const size_t wa =
                (((size_t)b * 32 + cb * 2 + seg) * NLT + tb * 128 + t) * 64 + c0;
            *(s16x8*)&WTg[wa] = *(const s16x8*)&WTs[t * 128 + c8];
        }
    }
}

// ---------------------------------------------------------------------------
// K2: g2c^T GEMM, tile 128 c x 256 d, BK=64, K=512 (=t). (R11-proven.)
// A = tgtTp packed panels via global_load_lds; B = Wp packed panels.
// ---------------------------------------------------------------------------
__global__ __launch_bounds__(256, 2) void k2_gemm(
    const unsigned short* __restrict__ Atp, const unsigned short* __restrict__ Wp,
    float* __restrict__ outp)
{
    __shared__ __align__(16) unsigned short Slds[2][256 * 64];   // [d][k] swz

    const int phys = blockIdx.x;
    const int L = (phys & 7) * 64 + (phys >> 3);   // grid 512, bijective
    const int b = L >> 4, cb = L & 15;
    float* outB = outp + ((size_t)b * (NLC + NLT) + cb * 128) * ND;

    const int tid = threadIdx.x, wave = tid >> 6, lane = tid & 63;
    const int lr = lane & 15, lq = lane >> 4;

    const int srow = tid >> 3;
    const int schunk = tid & 7;

    auto STAGE = [&](int buf, int ks) {
        #pragma unroll
        for (int i = 0; i < 8; ++i) {
            const int row = i * 32 + srow;
            const int gcol = schunk ^ (row & 7);
            glds16(Atp + (((size_t)b * 8 + ks) * 256 + row) * 64 + gcol * 8,
                   &Slds[buf][(i * 32 + wave * 8) * 64]);
        }
    };

    f32x4 acc[16][2];
    #pragma unroll
    for (int mf = 0; mf < 16; ++mf) { acc[mf][0] = (f32x4)(0.0f); acc[mf][1] = (f32x4)(0.0f); }

    STAGE(0, 0);
    for (int ks = 0; ks < 8; ++ks) {
        __syncthreads();
        const int buf = ks & 1;
        if (ks < 7) STAGE(buf ^ 1, ks + 1);

        s16x8 bfr[2][2];
        #pragma unroll
        for (int j = 0; j < 2; ++j)
            #pragma unroll
            for (int kk = 0; kk < 2; ++kk)
                bfr[j][kk] = *(const s16x8*)&Wp[
                    (((size_t)b * 8 + ks) * NLC + cb * 128 + wave * 32 + j * 16 + lr) * 64
                    + kk * 32 + lq * 8];

        __builtin_amdgcn_s_setprio(1);
        #pragma unroll
        for (int kk = 0; kk < 2; ++kk) {
            #pragma unroll
            for (int mf = 0; mf < 16; ++mf) {
                const int row = mf * 16 + lr;
                const s16x8 af = *(const s16x8*)&Slds[buf][row * 64 +
                                                           (((kk * 4 + lq) ^ (row & 7)) * 8)];
                acc[mf][0] = __builtin_amdgcn_mfma_f32_16x16x32_bf16(af, bfr[0][kk], acc[mf][0], 0, 0, 0);
                acc[mf][1] = __builtin_amdgcn_mfma_f32_16x16x32_bf16(af, bfr[1][kk], acc[mf][1], 0, 0, 0);
            }
        }
        __builtin_amdgcn_s_setprio(0);
    }

    #pragma unroll
    for (int j = 0; j < 2; ++j) {
        const int col = wave * 32 + j * 16 + lr;
        float* rp = outB + (size_t)col * ND;
        #pragma unroll
        for (int mf = 0; mf < 16; ++mf) {
            const f32x4 v = acc[mf][j];
            *(float4*)(rp + mf * 16 + lq * 4) = make_float4(v[0], v[1], v[2], v[3]);
        }
    }
}

// ---------------------------------------------------------------------------
// K3V5: g2t full-K, BOTH operands LDS-staged. (R11-proven.)
// Grid 256 = (b, tb of 128t, dh of 128d); block 512 thr / 8 waves (2d x 4t).
// ---------------------------------------------------------------------------
__global__ __launch_bounds__(512, 2) void k3v5(
    const unsigned short* __restrict__ ctxTp, const unsigned short* __restrict__ WTp,
    float* __restrict__ out)
{
    __shared__ __align__(16) unsigned short Alds[2][128 * 64];   // [d][k] swz
    __shared__ __align__(16) unsigned short Blds[2][128 * 64];   // [t][k] swz

    const int phys = blockIdx.x;
    const int L = (phys & 7) * 32 + (phys >> 3);   // grid 256, bijective
    const int b = L >> 3, r = L & 7;
    const int tb = r >> 1, dh = r & 1;

    const int tid = threadIdx.x, wave = tid >> 6, lane = tid & 63;
    const int lr = lane & 15, lq = lane >> 4;
    const int wd = wave >> 2, wt = wave & 3;   // 2 d-halves x 4 t-quarters

    auto STAGE = [&](int buf, int ks) {
        #pragma unroll
        for (int i = 0; i < 2; ++i) {
            const int q = wave * 2 + i;                 // 0..15
            const int rloc = q * 8 + (lane >> 3);       // 0..127
            const int gcol = (lane & 7) ^ (rloc & 7);
            glds16(ctxTp + (((size_t)b * 32 + ks) * 256 + dh * 128 + rloc) * 64 + gcol * 8,
                   &Alds[buf][q * 512]);
            glds16(WTp + (((size_t)b * 32 + ks) * NLT + tb * 128 + rloc) * 64 + gcol * 8,
                   &Blds[buf][q * 512]);
        }
    };

    f32x4 acc[4][2];   // [mf d-frag][nf t-frag]
    #pragma unroll
    for (int mf = 0; mf < 4; ++mf) { acc[mf][0] = (f32x4)(0.0f); acc[mf][1] = (f32x4)(0.0f); }

    STAGE(0, 0);
    for (int ks = 0; ks < 32; ++ks) {
        __syncthreads();
        const int buf = ks & 1;
        if (ks < 31) STAGE(buf ^ 1, ks + 1);

        __builtin_amdgcn_s_setprio(1);
        #pragma unroll
        for (int kk = 0; kk < 2; ++kk) {
            s16x8 bfr[2];
            #pragma unroll
            for (int nf = 0; nf < 2; ++nf) {
                const int row = wt * 32 + nf * 16 + lr;
                bfr[nf] = *(const s16x8*)&Blds[buf][row * 64 + (((kk * 4 + lq) ^ (row & 7)) * 8)];
            }
            #pragma unroll
            for (int mf = 0; mf < 4; ++mf) {
                const int row = wd * 64 + mf * 16 + lr;
                const s16x8 af = *(const s16x8*)&Alds[buf][row * 64 +
                                                           (((kk * 4 + lq) ^ (row & 7)) * 8)];
                acc[mf][0] = __builtin_amdgcn_mfma_f32_16x16x32_bf16(af, bfr[0], acc[mf][0], 0, 0, 0);
                acc[mf][1] = __builtin_amdgcn_mfma_f32_16x16x32_bf16(af, bfr[1], acc[mf][1], 0, 0, 0);
            }
        }
        __builtin_amdgcn_s_setprio(0);
    }

    #pragma unroll
    for (int nf = 0; nf < 2; ++nf) {
        const int t = tb * 128 + wt * 32 + nf * 16 + lr;
        float* rp = out + ((size_t)b * (NLC + NLT) + NLC + t) * ND + dh * 128 + wd * 64;
        #pragma unroll
        for (int mf = 0; mf < 4; ++mf) {
            const f32x4 v = acc[mf][nf];
            *(float4*)(rp + mf * 16 + lq * 4) = make_float4(v[0], v[1], v[2], v[3]);
        }
    }
}

// ===========================================================================
// R4 fused fallback (proven-correct) for small workspaces.
// ===========================================================================
__global__ __launch_bounds__(256) void zero_g2t(float* __restrict__ out) {
    const int g = blockIdx.x * 256 + threadIdx.x;
    #pragma unroll
    for (int k = 0; k < 4; ++k) {
        const int i = g + k * 262144;
        const int bb = i >> 15;
        const int off = i & 32767;
        *(float4*)(out + ((size_t)bb * (NLC + NLT) + NLC) * ND + (size_t)off * 4) =
            make_float4(0.f, 0.f, 0.f, 0.f);
    }
}

__global__ __launch_bounds__(256) void reduce_g2t(const float* __restrict__ part,
                                                  float* __restrict__ out) {
    const int g = blockIdx.x * 256 + threadIdx.x;
    #pragma unroll
    for (int k = 0; k < 4; ++k) {
        const int i = g + k * 262144;
        const int b = i >> 15;
        const int rem = i & 32767;
        const int row = rem >> 6;
        const int d4 = (rem & 63) * 4;
        const int mb = row >> 7, rr = row & 127;
        const size_t base = ((size_t)(b * 16 + mb * 4) * 32768) + (size_t)rr * 256 + d4;
        float4 s0 = *(const float4*)(part + base);
        float4 s1 = *(const float4*)(part + base + 32768);
        float4 s2 = *(const float4*)(part + base + 65536);
        float4 s3 = *(const float4*)(part + base + 98304);
        *(float4*)(out + ((size_t)b * (NLC + NLT) + NLC + row) * ND + d4) =
            make_float4(s0.x + s1.x + s2.x + s3.x, s0.y + s1.y + s2.y + s3.y,
                        s0.z + s1.z + s2.z + s3.z, s0.w + s1.w + s2.w + s3.w);
    }
}

__global__ __launch_bounds__(256, 2) void fused_dist_attn(
    const float* __restrict__ ctx, const float* __restrict__ tgt,
    float* __restrict__ out, float* __restrict__ part)
{
    __shared__ __align__(16) unsigned short Klds[2][32 * 256];
    __shared__ __align__(16) unsigned short VTlds[2][256 * 32];
    __shared__ __align__(16) unsigned short Wlds[4 * 32 * 32];
    __shared__ unsigned int KextLds[2][32];

    const int phys = blockIdx.x;
    const int L = (phys & 7) * 128 + (phys >> 3);
    const int isB = (L & 1) == 0;
    const int idx = L >> 1;
    const int b = idx >> 4;
    const float *Q, *KV;
    size_t outbase;
    if (isB) {
        const int mb = (idx >> 2) & 3, nc = idx & 3;
        Q = tgt + ((size_t)b * NLT + mb * 128) * ND;
        KV = ctx + ((size_t)b * NLC + nc * NCHUNK) * ND;
        outbase = ((size_t)b * (NLC + NLT) + NLC + mb * 128) * ND;
    } else {
        const int mb = idx & 15;
        Q = ctx + ((size_t)b * NLC + mb * 128) * ND;
        KV = tgt + (size_t)b * NLT * ND;
        outbase = ((size_t)b * (NLC + NLT) + mb * 128) * ND;
    }

    const int tid = threadIdx.x, wave = tid >> 6, lane = tid & 63;
    const int lr = lane & 15, lq = lane >> 4;

    s16x8 qf[2][8];
    s16x8 qe[2];
    #pragma unroll
    for (int mf = 0; mf < 2; ++mf) {
        const float* qrow = Q + (size_t)(wave * 32 + mf * 16 + lr) * ND;
        float q2 = 0.0f;
        #pragma unroll
        for (int kk = 0; kk < 8; ++kk) {
            const float4 a = *(const float4*)(qrow + kk * 32 + lq * 8);
            const float4 c = *(const float4*)(qrow + kk * 32 + lq * 8 + 4);
            q2 += a.x*a.x + a.y*a.y + a.z*a.z + a.w*a.w;
            q2 += c.x*c.x + c.y*c.y + c.z*c.z + c.w*c.w;
            qf[mf][kk] = cvt8(a, c, -2.0f);
        }
        q2 += __shfl_xor(q2, 16);
        q2 += __shfl_xor(q2, 32);
        union { unsigned int u[4]; s16x8 v; } qu;
        qu.u[0] = (lq == 0) ? (0x3F80u | ((unsigned int)f2bf(q2) << 16)) : 0u;
        qu.u[1] = 0u; qu.u[2] = 0u; qu.u[3] = 0u;
        qe[mf] = qu.v;
    }

    f32x4 acc[2][16];
    #pragma unroll
    for (int mf = 0; mf < 2; ++mf)
        #pragma unroll
        for (int dt = 0; dt < 16; ++dt)
            acc[mf][dt] = (f32x4)(0.0f);

    const int r4 = 8 * wave + 4 * (lane & 1);
    const int d8 = (lane >> 1) * 8;
    float4 ldr[4][2];

    auto LOADT = [&](int n0) {
        #pragma unroll
        for (int rr = 0; rr < 4; ++rr)
            #pragma unroll
            for (int h = 0; h < 2; ++h)
                ldr[rr][h] = *(const float4*)(KV + (size_t)(n0 + r4 + rr) * ND + d8 + 4 * h);
    };

    auto WRITET = [&](int sel) {
        float ps[4];
        unsigned short kb[4][8];
        #pragma unroll
        for (int rr = 0; rr < 4; ++rr) {
            const float4 a = ldr[rr][0], c = ldr[rr][1];
            ps[rr] = a.x*a.x + a.y*a.y + a.z*a.z + a.w*a.w
                   + c.x*c.x + c.y*c.y + c.z*c.z + c.w*c.w;
            kb[rr][0]=f2bf(a.x); kb[rr][1]=f2bf(a.y); kb[rr][2]=f2bf(a.z); kb[rr][3]=f2bf(a.w);
            kb[rr][4]=f2bf(c.x); kb[rr][5]=f2bf(c.y); kb[rr][6]=f2bf(c.z); kb[rr][7]=f2bf(c.w);
            const int rx = r4 + rr;
            *(s16x8*)&Klds[sel][rx * 256 + (d8 ^ ((rx & 7) << 3))] = *(const s16x8*)kb[rr];
        }
        #pragma unroll
        for (int dd = 0; dd < 8; ++dd) {
            const int d = d8 + dd;
            *(ushort4*)&VTlds[sel][d * 32 + (r4 ^ (((d >> 3) & 3) << 3))] =
                make_ushort4(kb[0][dd], kb[1][dd], kb[2][dd], kb[3][dd]);
        }
        #pragma unroll
        for (int rr = 0; rr < 4; ++rr) {
            ps[rr] += __shfl_xor(ps[rr], 2);
            ps[rr] += __shfl_xor(ps[rr], 4);
            ps[rr] += __shfl_xor(ps[rr], 8);
            ps[rr] += __shfl_xor(ps[rr], 16);
            ps[rr] += __shfl_xor(ps[rr], 32);
        }
        if (lane < 2) {
            #pragma unroll
            for (int rr = 0; rr < 4; ++rr)
                KextLds[sel][8 * wave + 4 * lane + rr] =
                    (unsigned int)f2bf(ps[rr]) | 0x3F800000u;
        }
    };

    LOADT(0);
    WRITET(0);

    #pragma unroll 2
    for (int t = 0; t < NITER; ++t) {
        __syncthreads();
        const int sel = t & 1;
        if (t + 1 < NITER) LOADT((t + 1) * 32);

        unsigned int p0 = 0u, p1 = 0u;
        if (lq == 0) { p0 = KextLds[sel][lr]; p1 = KextLds[sel][16 + lr]; }
        union { unsigned int u[4]; s16x8 v; } keu0, keu1;
        keu0.u[0] = p0; keu0.u[1] = 0; keu0.u[2] = 0; keu0.u[3] = 0;
        keu1.u[0] = p1; keu1.u[1] = 0; keu1.u[2] = 0; keu1.u[3] = 0;

        f32x4 sacc[2][2];
        sacc[0][0] = (f32x4)(0.0f); sacc[0][1] = (f32x4)(0.0f);
        sacc[1][0] = (f32x4)(0.0f); sacc[1][1] = (f32x4)(0.0f);
        __builtin_amdgcn_s_setprio(1);
        #pragma unroll
        for (int kk = 0; kk < 8; ++kk) {
            const int cs = (kk * 32 + lq * 8) ^ ((lr & 7) << 3);
            const s16x8 kf0 = *(const s16x8*)&Klds[sel][lr * 256 + cs];
            const s16x8 kf1 = *(const s16x8*)&Klds[sel][(16 + lr) * 256 + cs];
            sacc[0][0] = __builtin_amdgcn_mfma_f32_16x16x32_bf16(kf0, qf[0][kk], sacc[0][0], 0, 0, 0);
            sacc[0][1] = __builtin_amdgcn_mfma_f32_16x16x32_bf16(kf0, qf[1][kk], sacc[0][1], 0, 0, 0);
            sacc[1][0] = __builtin_amdgcn_mfma_f32_16x16x32_bf16(kf1, qf[0][kk], sacc[1][0], 0, 0, 0);
            sacc[1][1] = __builtin_amdgcn_mfma_f32_16x16x32_bf16(kf1, qf[1][kk], sacc[1][1], 0, 0, 0);
        }
        sacc[0][0] = __builtin_amdgcn_mfma_f32_16x16x32_bf16(keu0.v, qe[0], sacc[0][0], 0, 0, 0);
        sacc[0][1] = __builtin_amdgcn_mfma_f32_16x16x32_bf16(keu0.v, qe[1], sacc[0][1], 0, 0, 0);
        sacc[1][0] = __builtin_amdgcn_mfma_f32_16x16x32_bf16(keu1.v, qe[0], sacc[1][0], 0, 0, 0);
        sacc[1][1] = __builtin_amdgcn_mfma_f32_16x16x32_bf16(keu1.v, qe[1], sacc[1][1], 0, 0, 0);
        __builtin_amdgcn_s_setprio(0);

        #pragma unroll
        for (int ns = 0; ns < 2; ++ns) {
            #pragma unroll
            for (int mf = 0; mf < 2; ++mf) {
                unsigned short w4[4];
                #pragma unroll
                for (int j = 0; j < 4; ++j) {
                    float d2 = sacc[ns][mf][j];
                    d2 = d2 > 0.0f ? d2 : 0.0f;
                    w4[j] = f2bf(__builtin_amdgcn_rcpf(1.0f + __builtin_amdgcn_sqrtf(d2)));
                }
                const int row = mf * 16 + lr;
                const int col = (ns * 16 + lq * 4) ^ ((row & 3) << 3);
                *(ushort4*)&Wlds[wave * 1024 + row * 32 + col] =
                    make_ushort4(w4[0], w4[1], w4[2], w4[3]);
            }
        }

        s16x8 wfr[2];
        #pragma unroll
        for (int mf = 0; mf < 2; ++mf)
            wfr[mf] = *(const s16x8*)&Wlds[wave * 1024 + (mf * 16 + lr) * 32 +
                                           ((lq * 8) ^ ((lr & 3) << 3))];
        __builtin_amdgcn_s_setprio(1);
        #pragma unroll
        for (int dt = 0; dt < 16; ++dt) {
            const int vr = dt * 16 + lr;
            const s16x8 vf = *(const s16x8*)&VTlds[sel][vr * 32 +
                                                        ((lq * 8) ^ (((vr >> 3) & 3) << 3))];
            acc[0][dt] = __builtin_amdgcn_mfma_f32_16x16x32_bf16(vf, wfr[0], acc[0][dt], 0, 0, 0);
            acc[1][dt] = __builtin_amdgcn_mfma_f32_16x16x32_bf16(vf, wfr[1], acc[1][dt], 0, 0, 0);
        }
        __builtin_amdgcn_s_setprio(0);

        if (t + 1 < NITER) WRITET(sel ^ 1);
    }

    if (isB) {
        if (part) {
            float* p = part + (size_t)idx * 32768;
            #pragma unroll
            for (int mf = 0; mf < 2; ++mf) {
                const size_t rowbase = (size_t)(wave * 32 + mf * 16 + lr) * ND;
                #pragma unroll
                for (int dt = 0; dt < 16; ++dt) {
                    const f32x4 v = acc[mf][dt];
                    *(float4*)(p + rowbase + dt * 16 + lq * 4) = make_float4(v[0], v[1], v[2], v[3]);
                }
            }
        } else {
            #pragma unroll
            for (int mf = 0; mf < 2; ++mf) {
                float* rowp = out + outbase + (size_t)(wave * 32 + mf * 16 + lr) * ND;
                #pragma unroll
                for (int dt = 0; dt < 16; ++dt)
                    #pragma unroll
                    for (int j = 0; j < 4; ++j)
                        atomicAdd(rowp + dt * 16 + lq * 4 + j, acc[mf][dt][j]);
            }
        }
    } else {
        #pragma unroll
        for (int mf = 0; mf < 2; ++mf) {
            const size_t rowbase = outbase + (size_t)(wave * 32 + mf * 16 + lr) * ND;
            #pragma unroll
            for (int dt = 0; dt < 16; ++dt) {
                const f32x4 v = acc[mf][dt];
                *(float4*)(out + rowbase + dt * 16 + lq * 4) = make_float4(v[0], v[1], v[2], v[3]);
            }
        }
    }
}

extern "C" void kernel_launch(void* const* d_in, const int* in_sizes, int n_in,
                              void* d_out, int out_size, void* d_ws, size_t ws_size,
                              hipStream_t stream) {
    const float* ctx = (const float*)d_in[0];   // [32, 2048, 256] fp32
    const float* tgt = (const float*)d_in[1];   // [32, 512, 256] fp32
    float* out = (float*)d_out;                 // [32, 2560, 256] fp32

    const size_t OFF_NORMS = 0;
    const size_t OFF_CTXB  = 327680;
    const size_t OFF_TGTB  = OFF_CTXB + 33554432;
    const size_t OFF_CTXT  = OFF_TGTB + 8388608;
    const size_t OFF_TGTT  = OFF_CTXT + 33554432;
    const size_t OFF_W     = OFF_TGTT + 8388608;
    const size_t OFF_WT    = OFF_W + 67108864;
    const size_t NEED_NEW  = OFF_WT + 67108864;   // 218,431,488 (proven available)

    char* ws = (char*)d_ws;
    if (ws_size >= NEED_NEW) {
        float* norms = (float*)(ws + OFF_NORMS);
        unsigned short* ctxb  = (unsigned short*)(ws + OFF_CTXB);
        unsigned short* tgtb  = (unsigned short*)(ws + OFF_TGTB);
        unsigned short* ctxTp = (unsigned short*)(ws + OFF_CTXT);
        unsigned short* tgtTp = (unsigned short*)(ws + OFF_TGTT);
        unsigned short* Wg    = (unsigned short*)(ws + OFF_W);
        unsigned short* WTg   = (unsigned short*)(ws + OFF_WT);

        prep_kernel<<<20480, 256, 0, stream>>>(ctx, tgt, norms, ctxb, tgtb);
        transpose_bf<<<5120, 256, 0, stream>>>(ctxb, tgtb, ctxTp, tgtTp);
        k1_weights<<<2048, 256, 0, stream>>>(ctxb, tgtb, norms, Wg, WTg);
        k2_gemm<<<512, 256, 0, stream>>>(tgtTp, Wg, out);
        k3v5<<<256, 512, 0, stream>>>(ctxTp, WTg, out);
    } else {
        const size_t need = (size_t)512 * 128 * 256 * 4;
        if (ws_size >= need) {
            float* part = (float*)d_ws;
            fused_dist_attn<<<1024, 256, 0, stream>>>(ctx, tgt, out, part);
            reduce_g2t<<<1024, 256, 0, stream>>>(part, out);
        } else {
            zero_g2t<<<1024, 256, 0, stream>>>(out);
            fused_dist_attn<<<1024, 256, 0, stream>>>(ctx, tgt, out, nullptr);
        }
    }
}